// Round 1
// baseline (1723.081 us; speedup 1.0000x reference)
//
#include <hip/hip_runtime.h>

// Problem constants (fixed by the reference).
constexpr int N_   = 1024;
constexpr int K_   = 32;
constexpr int ISZ  = 10000;
constexpr int ROWS = N_ * K_;            // 32768 (n,k) rows
constexpr int V4   = ISZ / 4;            // 2500 float4 per row
constexpr int FULL = V4 / 64;            // 39 full wave iterations (2496 vec4)
constexpr int TAIL = V4 - FULL * 64;     // 4 leftover vec4 (lanes 0..3)

constexpr float EPS   = 1e-10f;
constexpr float C_LG  = 3.0f / 10.0f;    // LR_MULTIPLIER / TEMPERATURE
constexpr float C_G   = 1.0f / 10.0f;    // 1 / TEMPERATURE

// gumbel = -log(-log(u+eps)+eps); s = 0.3*lg - 0.1*log(eps - log(u+eps))
__device__ __forceinline__ void acc_elem(float uu, float xx, float lg,
                                         float& sum, float& dot) {
    float l1 = __logf(uu + EPS);                 // log(u+eps)  (negative)
    float l2 = __logf(EPS - l1);                 // log(-log(u+eps)+eps)
    float e  = __expf(fmaf(C_LG, lg, -C_G * l2)); // exp(score); bounded, no overflow
    sum += e;
    dot = fmaf(xx, e, dot);
}

__global__ __launch_bounds__(256, 4) void cs_kernel(
    const float* __restrict__ x,       // (N, ISZ)
    const float* __restrict__ u,       // (N, K, ISZ)
    const float* __restrict__ logits,  // (K, ISZ)
    float* __restrict__ out)           // (N, K)
{
    const int wave = threadIdx.x >> 6;
    const int lane = threadIdx.x & 63;

    // 8192 blocks; consecutive blockIdx round-robin across 8 XCDs.
    // Remap so each XCD gets a CONTIGUOUS block range -> contiguous n range,
    // keeping x-row re-reads (32x reuse) inside one XCD's L2.
    const int b   = ((blockIdx.x & 7) << 10) | (blockIdx.x >> 3);
    const int row = b * 4 + wave;            // (n,k) row id
    const int n   = row >> 5;                // row / 32
    const int k   = row & 31;                // row % 32

    const float4* __restrict__ up = (const float4*)u      + (size_t)row * V4;
    const float4* __restrict__ xp = (const float4*)x      + (size_t)n   * V4;
    const float4* __restrict__ lp = (const float4*)logits + (size_t)k   * V4;

    float sum = 0.0f, dot = 0.0f;

    for (int it = 0; it < FULL; ++it) {
        const int idx = it * 64 + lane;
        const float4 uv = up[idx];
        const float4 xv = xp[idx];
        const float4 lv = lp[idx];
        acc_elem(uv.x, xv.x, lv.x, sum, dot);
        acc_elem(uv.y, xv.y, lv.y, sum, dot);
        acc_elem(uv.z, xv.z, lv.z, sum, dot);
        acc_elem(uv.w, xv.w, lv.w, sum, dot);
    }
    if (lane < TAIL) {
        const int idx = FULL * 64 + lane;
        const float4 uv = up[idx];
        const float4 xv = xp[idx];
        const float4 lv = lp[idx];
        acc_elem(uv.x, xv.x, lv.x, sum, dot);
        acc_elem(uv.y, xv.y, lv.y, sum, dot);
        acc_elem(uv.z, xv.z, lv.z, sum, dot);
        acc_elem(uv.w, xv.w, lv.w, sum, dot);
    }

    // wave-64 butterfly reduction
    #pragma unroll
    for (int off = 32; off > 0; off >>= 1) {
        sum += __shfl_down(sum, off);
        dot += __shfl_down(dot, off);
    }
    if (lane == 0) out[row] = dot / sum;
}

extern "C" void kernel_launch(void* const* d_in, const int* in_sizes, int n_in,
                              void* d_out, int out_size, void* d_ws, size_t ws_size,
                              hipStream_t stream) {
    const float* x      = (const float*)d_in[0];
    const float* u      = (const float*)d_in[1];
    const float* logits = (const float*)d_in[2];
    float* out = (float*)d_out;

    // 4 rows per block (one wave each) -> 8192 blocks
    cs_kernel<<<ROWS / 4, 256, 0, stream>>>(x, u, logits, out);
}